// Round 10
// baseline (1362.720 us; speedup 1.0000x reference)
//
#include <hip/hip_runtime.h>
#include <cstdint>

#define ALPHA 0.2f
#define H 256

typedef __attribute__((ext_vector_type(8))) short bf16x8;
typedef __attribute__((ext_vector_type(4))) float f32x4;

__device__ __forceinline__ float actf(float v){ return v > 0.0f ? v : ALPHA * v; }

__device__ __forceinline__ ushort f2b(float f){
  union { float f; uint u; } x; x.f = f;
  uint u = x.u + 0x7FFF + ((x.u >> 16) & 1);   // RNE
  return (ushort)(u >> 16);
}
__device__ __forceinline__ float b2f(ushort h){
  union { uint u; float f; } x; x.u = (uint)h << 16; return x.f;
}

__device__ __forceinline__ void gld_lds16(const void* g, void* l){
  __builtin_amdgcn_global_load_lds((const __attribute__((address_space(1))) void*)g,
                                   (__attribute__((address_space(3))) void*)l, 16, 0, 0);
}

// ---------------- CSR build (combined weighted neighbor list) ----------------
__global__ void k_deg(const int* __restrict__ src, const int* __restrict__ dst,
                      int* __restrict__ deg_s, int* __restrict__ deg_t, int nE){
  int e = blockIdx.x * blockDim.x + threadIdx.x;
  if (e < nE){
    atomicAdd(&deg_s[src[e]], 1);
    atomicAdd(&deg_t[src[e]], 1);
    atomicAdd(&deg_t[dst[e]], 1);
  }
}

__global__ void k_scale_off(const int* __restrict__ deg_s, const int* __restrict__ deg_t,
                            float* __restrict__ scale, int* __restrict__ off_t,
                            int* __restrict__ ctr, int nN){
  int n = blockIdx.x * blockDim.x + threadIdx.x;
  if (n < nN){
    scale[n] = 1.0f / (1.0f + (float)deg_s[n]);
    off_t[n] = atomicAdd(&ctr[0], deg_t[n]);
  }
}

__global__ void k_fill(const int* __restrict__ src, const int* __restrict__ dst,
                       const float* __restrict__ scale,
                       const int* __restrict__ off_t, int* __restrict__ cur,
                       int* __restrict__ nbr_all, float* __restrict__ wgt_all, int nE){
  int e = blockIdx.x * blockDim.x + threadIdx.x;
  if (e < nE){
    int s = src[e], d = dst[e];
    float w = scale[s];
    int p = atomicAdd(&cur[d], 1);
    int idx = off_t[d] + p;
    nbr_all[idx] = s; wgt_all[idx] = w;
    int q = atomicAdd(&cur[s], 1);
    idx = off_t[s] + q;
    nbr_all[idx] = d; wgt_all[idx] = w;
  }
}

// ---------------- coalesced weight transpose: Wt[n][k] = bf16(W[k][n]) ----------------
// 32x32 LDS tile: both global read (float, 128B/row) and write (ushort, 64B/row) coalesced.
__global__ __launch_bounds__(256) void k_tpose(const float* __restrict__ W,
                                               ushort* __restrict__ Wt, int K, int N){
  __shared__ ushort tile[32][33];
  int nt = N >> 5;
  int tr = blockIdx.x / nt, tc = blockIdx.x % nt;
  int r = threadIdx.x >> 5, c = threadIdx.x & 31;   // r: 0..7
#pragma unroll
  for (int i = 0; i < 4; i++){
    int rr = r + i * 8;
    tile[rr][c] = f2b(W[(size_t)(tr * 32 + rr) * N + tc * 32 + c]);
  }
  __syncthreads();
#pragma unroll
  for (int i = 0; i < 4; i++){
    int rr = r + i * 8;
    Wt[(size_t)(tc * 32 + rr) * K + tr * 32 + c] = tile[c][rr];
  }
}

__global__ void k_cvt(const float* __restrict__ src, ushort* __restrict__ dst, int n){
  int i = blockIdx.x * 256 + threadIdx.x;
  if (i < n) dst[i] = f2b(src[i]);
}

// ---------------- aggregation (round-6 proven version): act on the fly, unroll x8 ----
// aggb[n] = bf16( sum_i w_i * act(xb[nbr_i]) + (2*scale[n]+1) * act(xb[n]) )
__global__ __launch_bounds__(256) void k_agg(
    const ushort* __restrict__ xb, ushort* __restrict__ aggb, const float* __restrict__ scale,
    const int* __restrict__ off_t, const int* __restrict__ deg_t,
    const int* __restrict__ nbr_all, const float* __restrict__ wgt_all, int nN){
  int wave = threadIdx.x >> 6;
  int lane = threadIdx.x & 63;
  int n = blockIdx.x * 4 + wave;
  if (n >= nN) return;
  const uint2* xr = (const uint2*)xb;
  float sn = scale[n];

  uint2 v = xr[(size_t)n * 64 + lane];
  float c = 2.f * sn + 1.f;
  float r0 = c * actf(b2f((ushort)v.x)), r1 = c * actf(b2f((ushort)(v.x >> 16)));
  float r2 = c * actf(b2f((ushort)v.y)), r3 = c * actf(b2f((ushort)(v.y >> 16)));

  const int o = off_t[n], d = deg_t[n];
  int i = 0;
  for (; i + 8 <= d; i += 8){
    int u[8]; float w[8];
#pragma unroll
    for (int j = 0; j < 8; j++){ u[j] = nbr_all[o + i + j]; w[j] = wgt_all[o + i + j]; }
    uint2 t[8];
#pragma unroll
    for (int j = 0; j < 8; j++) t[j] = xr[(size_t)u[j] * 64 + lane];
#pragma unroll
    for (int j = 0; j < 8; j++){
      r0 += w[j] * actf(b2f((ushort)t[j].x)); r1 += w[j] * actf(b2f((ushort)(t[j].x >> 16)));
      r2 += w[j] * actf(b2f((ushort)t[j].y)); r3 += w[j] * actf(b2f((ushort)(t[j].y >> 16)));
    }
  }
  for (; i < d; i++){
    int u = nbr_all[o + i]; float w = wgt_all[o + i];
    uint2 t = xr[(size_t)u * 64 + lane];
    r0 += w * actf(b2f((ushort)t.x)); r1 += w * actf(b2f((ushort)(t.x >> 16)));
    r2 += w * actf(b2f((ushort)t.y)); r3 += w * actf(b2f((ushort)(t.y >> 16)));
  }

  uint2 out;
  out.x = (uint)f2b(r0) | ((uint)f2b(r1) << 16);
  out.y = (uint)f2b(r2) | ((uint)f2b(r3) << 16);
  ((uint2*)aggb)[(size_t)n * 64 + lane] = out;
}

// ---------------- fused 2-GEMM MLP layer (bf16 MFMA, M=32 tile, 16KB LDS) ----------------
// xb bf16 pre-activation, updated in place (resid read at epilogue, coalesced).
template<int K1, bool RESID, bool GATHER>
__global__ __launch_bounds__(256, 8) void k_fused_mlp(
    const ushort* __restrict__ Abase, const int* __restrict__ op_ids,
    const ushort* __restrict__ Wt1, const float* __restrict__ b1,
    const ushort* __restrict__ Wt2, const float* __restrict__ b2,
    ushort* __restrict__ xb, int nN)
{
  __shared__ ushort smem[32 * 256];    // 16 KiB -> 8 blocks/CU (32 waves)

  const int tid = threadIdx.x;
  const long m0 = (long)blockIdx.x * 32;
  const int wave = tid >> 6;
  const int lane = tid & 63;
  const int lr = lane & 15;
  const int lg = lane >> 4;
  const int n0 = wave * 64;
  const int aswz = (lr & 7) << 3;      // read-side swizzle (ushort units)

  // ---- stage A-tile (32 rows x K1) via global_load_lds, inverse-swizzled src ----
  {
    constexpr int ROWB = K1 * 2;
    constexpr int ROUNDS = (32 * ROWB) / 4096;
    char* lds_c = (char*)smem;
#pragma unroll
    for (int rr = 0; rr < ROUNDS; rr++){
      int b = rr * 4096 + tid * 16;
      int row = b / ROWB;
      int colb = b % ROWB;
      long rg = m0 + row; if (rg >= nN) rg = nN - 1;
      long srow = GATHER ? (long)op_ids[rg] : rg;
      const char* src = (const char*)Abase + srow * ROWB + (colb ^ ((row & 7) << 4));
      gld_lds16(src, lds_c + b);
    }
  }
  __syncthreads();

  const ushort* w1r[4]; const ushort* w2r[4];
#pragma unroll
  for (int ni = 0; ni < 4; ni++){
    w1r[ni] = Wt1 + (size_t)(n0 + ni * 16 + lr) * K1;
    w2r[ni] = Wt2 + (size_t)(n0 + ni * 16 + lr) * 256;
  }

  // ---- GEMM1: A @ W1 ----
  f32x4 acc[2][4];
#pragma unroll
  for (int mi = 0; mi < 2; mi++)
#pragma unroll
    for (int ni = 0; ni < 4; ni++) acc[mi][ni] = (f32x4){0.f,0.f,0.f,0.f};

  for (int ks = 0; ks < K1 / 32; ks++){
    int k = ks * 32 + lg * 8;
    bf16x8 af[2], bfr[4];
#pragma unroll
    for (int mi = 0; mi < 2; mi++){
      int idx = ((mi * 16 + lr) * K1 + k) ^ aswz;
      af[mi] = *(const bf16x8*)&smem[idx];
    }
#pragma unroll
    for (int ni = 0; ni < 4; ni++)
      bfr[ni] = *(const bf16x8*)(w1r[ni] + k);
#pragma unroll
    for (int mi = 0; mi < 2; mi++)
#pragma unroll
      for (int ni = 0; ni < 4; ni++)
        acc[mi][ni] = __builtin_amdgcn_mfma_f32_16x16x32_bf16(af[mi], bfr[ni], acc[mi][ni], 0, 0, 0);
  }
  __syncthreads();   // A-tile consumed

  // ---- act + bf16 -> h-tile in same LDS (semantic [32][256], same swizzle) ----
  float bb1[4];
#pragma unroll
  for (int ni = 0; ni < 4; ni++) bb1[ni] = b1[n0 + ni * 16 + lr];
#pragma unroll
  for (int mi = 0; mi < 2; mi++)
#pragma unroll
    for (int ni = 0; ni < 4; ni++)
#pragma unroll
      for (int r = 0; r < 4; r++){
        float v = actf(acc[mi][ni][r] + bb1[ni]);
        int row = mi * 16 + lg * 4 + r;
        int idx = (row * 256 + n0 + ni * 16 + lr) ^ ((row & 7) << 3);
        smem[idx] = f2b(v);
      }
  __syncthreads();

  // ---- GEMM2: h @ W2 ----
  f32x4 acc2[2][4];
#pragma unroll
  for (int mi = 0; mi < 2; mi++)
#pragma unroll
    for (int ni = 0; ni < 4; ni++) acc2[mi][ni] = (f32x4){0.f,0.f,0.f,0.f};

  for (int ks = 0; ks < 8; ks++){
    int k = ks * 32 + lg * 8;
    bf16x8 af[2], bfr[4];
#pragma unroll
    for (int mi = 0; mi < 2; mi++){
      int idx = ((mi * 16 + lr) * 256 + k) ^ aswz;
      af[mi] = *(const bf16x8*)&smem[idx];
    }
#pragma unroll
    for (int ni = 0; ni < 4; ni++)
      bfr[ni] = *(const bf16x8*)(w2r[ni] + k);
#pragma unroll
    for (int mi = 0; mi < 2; mi++)
#pragma unroll
      for (int ni = 0; ni < 4; ni++)
        acc2[mi][ni] = __builtin_amdgcn_mfma_f32_16x16x32_bf16(af[mi], bfr[ni], acc2[mi][ni], 0, 0, 0);
  }
  __syncthreads();   // h-tile consumed; smem reusable

  // ---- result tile (acc2 + b2, bf16) -> LDS, swizzled ----
  float bb2[4];
#pragma unroll
  for (int ni = 0; ni < 4; ni++) bb2[ni] = b2[n0 + ni * 16 + lr];
#pragma unroll
  for (int mi = 0; mi < 2; mi++)
#pragma unroll
    for (int ni = 0; ni < 4; ni++)
#pragma unroll
      for (int r = 0; r < 4; r++){
        int row = mi * 16 + lg * 4 + r;
        int idx = (row * 256 + n0 + ni * 16 + lr) ^ ((row & 7) << 3);
        smem[idx] = f2b(acc2[mi][ni][r] + bb2[ni]);
      }
  __syncthreads();

  // ---- coalesced epilogue: 16B chunks; resid read+add elementwise (round-6 style) ----
#pragma unroll
  for (int rr = 0; rr < 4; rr++){
    int b = rr * 4096 + tid * 16;
    int row = b >> 9;
    long rg = m0 + row;
    if (rg < nN){
      int rb = b & 511;
      uint4 hv = *(const uint4*)((const char*)smem + row * 512 + (rb ^ ((row & 7) << 4)));
      uint4 ov;
      if (RESID){
        uint4 rv = *(const uint4*)((const char*)xb + rg * 512 + rb);
        const ushort* hp = (const ushort*)&hv;
        const ushort* rp = (const ushort*)&rv;
        ushort* op = (ushort*)&ov;
#pragma unroll
        for (int j = 0; j < 8; j++) op[j] = f2b(b2f(hp[j]) + b2f(rp[j]));
      } else {
        ov = hv;
      }
      *(uint4*)((char*)xb + rg * 512 + rb) = ov;
    }
  }
}

// ---------------- pooling: pooled[g] += act(xb[n]) ----------------
__global__ __launch_bounds__(256) void k_pool(const ushort* __restrict__ xb,
                                              const int* __restrict__ gids,
                                              float* __restrict__ pooled, int nN){
  int j = threadIdx.x;
  int base = blockIdx.x * 256;
  if (base >= nN) return;
  int end = base + 256; if (end > nN) end = nN;
  float acc = 0.f;
  int gcur = gids[base];
  for (int n = base; n < end; n++){
    int g = gids[n];
    if (g != gcur){
      atomicAdd(&pooled[gcur * H + j], acc);
      acc = 0.f; gcur = g;
    }
    acc += actf(b2f(xb[(size_t)n * H + j]));
  }
  atomicAdd(&pooled[gcur * H + j], acc);
}

// ---------------- post MLP ----------------
__global__ __launch_bounds__(256) void k_post(const float* __restrict__ pooled,
                                              const float* __restrict__ W1, const float* __restrict__ b1,
                                              const float* __restrict__ W2, const float* __restrict__ b2,
                                              float* __restrict__ out){
  __shared__ float sp[H];
  __shared__ float red[256];
  int g = blockIdx.x, j = threadIdx.x;
  sp[j] = pooled[g * H + j];
  __syncthreads();
  float acc = 0.f;
  for (int k = 0; k < H; k++) acc += sp[k] * W1[k * H + j];
  acc = actf(acc + b1[j]);
  red[j] = acc * W2[j];
  __syncthreads();
  for (int s = 128; s > 0; s >>= 1){
    if (j < s) red[j] += red[j + s];
    __syncthreads();
  }
  if (j == 0) out[g] = red[0] + b2[0];
}

extern "C" void kernel_launch(void* const* d_in, const int* in_sizes, int n_in,
                              void* d_out, int out_size, void* d_ws, size_t ws_size,
                              hipStream_t stream){
  const int*   op_ids = (const int*)d_in[0];
  const int*   esrc   = (const int*)d_in[1];
  const int*   edst   = (const int*)d_in[2];
  const int*   gids   = (const int*)d_in[3];
  const float* emb    = (const float*)d_in[4];
  const float* pW1    = (const float*)d_in[5];
  const float* pb1    = (const float*)d_in[6];
  const float* pW2    = (const float*)d_in[7];
  const float* pb2    = (const float*)d_in[8];
  const float* gW1    = (const float*)d_in[9];
  const float* gb1    = (const float*)d_in[10];
  const float* gW2    = (const float*)d_in[11];
  const float* gb2    = (const float*)d_in[12];
  const float* qW1    = (const float*)d_in[13];
  const float* qb1    = (const float*)d_in[14];
  const float* qW2    = (const float*)d_in[15];
  const float* qb2    = (const float*)d_in[16];

  int nN = in_sizes[0];
  int nE = in_sizes[1];
  int nG = out_size;
  int nEmb = in_sizes[4];

  char* ws = (char*)d_ws;
  size_t off = 0;
  auto alloc = [&](size_t bytes)->char* {
    char* p = ws + off;
    off += (bytes + 255) & ~(size_t)255;
    return p;
  };
  ushort* xb      = (ushort*)alloc((size_t)nN * H * 2);
  ushort* aggb    = (ushort*)alloc((size_t)nN * H * 2);
  float*  scale   = (float*) alloc((size_t)nN * 4);
  int*    nbr_all = (int*)   alloc((size_t)2 * nE * 4);
  float*  wgt_all = (float*) alloc((size_t)2 * nE * 4);
  int*    off_t   = (int*)   alloc((size_t)nN * 4);
  ushort* embb    = (ushort*)alloc((size_t)nEmb * 2);
  ushort* wtp1    = (ushort*)alloc((size_t)64 * 256 * 2);
  ushort* wtp2    = (ushort*)alloc((size_t)256 * 256 * 2);
  ushort* wtg     = (ushort*)alloc((size_t)6 * 256 * 256 * 2);
  char*   zbase   = ws + off;
  int*    deg_s   = (int*)   alloc((size_t)nN * 4);
  int*    deg_t   = (int*)   alloc((size_t)nN * 4);
  int*    cur     = (int*)   alloc((size_t)nN * 4);
  int*    ctr     = (int*)   alloc(256);
  float*  pooled  = (float*) alloc((size_t)nG * H * 4);
  size_t zbytes = (size_t)((ws + off) - zbase);

  hipMemsetAsync(zbase, 0, zbytes, stream);

  const int tb = 256;
  k_deg<<<(nE + tb - 1)/tb, tb, 0, stream>>>(esrc, edst, deg_s, deg_t, nE);
  k_scale_off<<<(nN + tb - 1)/tb, tb, 0, stream>>>(deg_s, deg_t, scale, off_t, ctr, nN);
  k_fill<<<(nE + tb - 1)/tb, tb, 0, stream>>>(esrc, edst, scale, off_t, cur, nbr_all, wgt_all, nE);

  // weight prep: coalesced LDS-tiled transposes + emb cast
  k_cvt<<<(nEmb + 255)/256, 256, 0, stream>>>(emb, embb, nEmb);
  k_tpose<<<(64/32)*(256/32), 256, 0, stream>>>(pW1, wtp1, 64, 256);
  k_tpose<<<(256/32)*(256/32), 256, 0, stream>>>(pW2, wtp2, 256, 256);
  for (int i = 0; i < 3; i++){
    k_tpose<<<64, 256, 0, stream>>>(gW1 + (size_t)i*65536, wtg + (size_t)(2*i)*65536, 256, 256);
    k_tpose<<<64, 256, 0, stream>>>(gW2 + (size_t)i*65536, wtg + (size_t)(2*i+1)*65536, 256, 256);
  }

  int gblk = (nN + 31) / 32;
  // prenet: xb = act(emb[op]@W1+b1)@W2+b2
  k_fused_mlp<64, false, true><<<gblk, 256, 0, stream>>>(
      embb, op_ids, wtp1, pb1, wtp2, pb2, xb, nN);

  for (int i = 0; i < 3; i++){
    k_agg<<<(nN + 3)/4, 256, 0, stream>>>(xb, aggb, scale, off_t, deg_t, nbr_all, wgt_all, nN);
    k_fused_mlp<256, true, false><<<gblk, 256, 0, stream>>>(
        aggb, op_ids, wtg + (size_t)(2*i)*65536, gb1 + (size_t)i*H,
        wtg + (size_t)(2*i+1)*65536, gb2 + (size_t)i*H, xb, nN);
  }

  k_pool<<<(nN + 255)/256, 256, 0, stream>>>(xb, gids, pooled, nN);
  k_post<<<nG, 256, 0, stream>>>(pooled, qW1, qb1, qW2, qb2, (float*)d_out);
}

// Round 11
// 1144.582 us; speedup vs baseline: 1.1906x; 1.1906x over previous
//
#include <hip/hip_runtime.h>
#include <cstdint>

#define ALPHA 0.2f
#define H 256

typedef __attribute__((ext_vector_type(8))) short bf16x8;
typedef __attribute__((ext_vector_type(4))) float f32x4;

__device__ __forceinline__ float actf(float v){ return v > 0.0f ? v : ALPHA * v; }

__device__ __forceinline__ ushort f2b(float f){
  union { float f; uint u; } x; x.f = f;
  uint u = x.u + 0x7FFF + ((x.u >> 16) & 1);   // RNE
  return (ushort)(u >> 16);
}
__device__ __forceinline__ float b2f(ushort h){
  union { uint u; float f; } x; x.u = (uint)h << 16; return x.f;
}

__device__ __forceinline__ void gld_lds16(const void* g, void* l){
  __builtin_amdgcn_global_load_lds((const __attribute__((address_space(1))) void*)g,
                                   (__attribute__((address_space(3))) void*)l, 16, 0, 0);
}

// ---------------- CSR build (combined weighted neighbor list) ----------------
__global__ void k_deg(const int* __restrict__ src, const int* __restrict__ dst,
                      int* __restrict__ deg_s, int* __restrict__ deg_t, int nE){
  int e = blockIdx.x * blockDim.x + threadIdx.x;
  if (e < nE){
    atomicAdd(&deg_s[src[e]], 1);
    atomicAdd(&deg_t[src[e]], 1);
    atomicAdd(&deg_t[dst[e]], 1);
  }
}

__global__ void k_scale_off(const int* __restrict__ deg_s, const int* __restrict__ deg_t,
                            float* __restrict__ scale, int* __restrict__ off_t,
                            int* __restrict__ ctr, int nN){
  int n = blockIdx.x * blockDim.x + threadIdx.x;
  if (n < nN){
    scale[n] = 1.0f / (1.0f + (float)deg_s[n]);
    off_t[n] = atomicAdd(&ctr[0], deg_t[n]);
  }
}

__global__ void k_fill(const int* __restrict__ src, const int* __restrict__ dst,
                       const float* __restrict__ scale,
                       const int* __restrict__ off_t, int* __restrict__ cur,
                       int* __restrict__ nbr_all, float* __restrict__ wgt_all, int nE){
  int e = blockIdx.x * blockDim.x + threadIdx.x;
  if (e < nE){
    int s = src[e], d = dst[e];
    float w = scale[s];
    int p = atomicAdd(&cur[d], 1);
    int idx = off_t[d] + p;
    nbr_all[idx] = s; wgt_all[idx] = w;
    int q = atomicAdd(&cur[s], 1);
    idx = off_t[s] + q;
    nbr_all[idx] = d; wgt_all[idx] = w;
  }
}

// ---------------- coalesced weight transpose: Wt[n][k] = bf16(W[k][n]) ----------------
__global__ __launch_bounds__(256) void k_tpose(const float* __restrict__ W,
                                               ushort* __restrict__ Wt, int K, int N){
  __shared__ ushort tile[32][33];
  int nt = N >> 5;
  int tr = blockIdx.x / nt, tc = blockIdx.x % nt;
  int r = threadIdx.x >> 5, c = threadIdx.x & 31;
#pragma unroll
  for (int i = 0; i < 4; i++){
    int rr = r + i * 8;
    tile[rr][c] = f2b(W[(size_t)(tr * 32 + rr) * N + tc * 32 + c]);
  }
  __syncthreads();
#pragma unroll
  for (int i = 0; i < 4; i++){
    int rr = r + i * 8;
    Wt[(size_t)(tc * 32 + rr) * K + tr * 32 + c] = tile[c][rr];
  }
}

__global__ void k_cvt(const float* __restrict__ src, ushort* __restrict__ dst, int n){
  int i = blockIdx.x * 256 + threadIdx.x;
  if (i < n) dst[i] = f2b(src[i]);
}

// ---------------- aggregation (R4-proven): reads pre-activated axb, unroll x8 ----
// aggb[n] = bf16( sum_i w_i * a[nbr_i] + (2*scale[n]+1) * a[n] ),  a = axb
__global__ __launch_bounds__(256) void k_agg(
    const ushort* __restrict__ axb, ushort* __restrict__ aggb, const float* __restrict__ scale,
    const int* __restrict__ off_t, const int* __restrict__ deg_t,
    const int* __restrict__ nbr_all, const float* __restrict__ wgt_all, int nN){
  int wave = threadIdx.x >> 6;
  int lane = threadIdx.x & 63;
  int n = blockIdx.x * 4 + wave;
  if (n >= nN) return;
  const uint2* xr = (const uint2*)axb;
  float sn = scale[n];

  uint2 v = xr[(size_t)n * 64 + lane];
  float c = 2.f * sn + 1.f;
  float r0 = c * b2f((ushort)v.x), r1 = c * b2f((ushort)(v.x >> 16));
  float r2 = c * b2f((ushort)v.y), r3 = c * b2f((ushort)(v.y >> 16));

  const int o = off_t[n], d = deg_t[n];
  int i = 0;
  for (; i + 8 <= d; i += 8){
    int u[8]; float w[8];
#pragma unroll
    for (int j = 0; j < 8; j++){ u[j] = nbr_all[o + i + j]; w[j] = wgt_all[o + i + j]; }
    uint2 t[8];
#pragma unroll
    for (int j = 0; j < 8; j++) t[j] = xr[(size_t)u[j] * 64 + lane];
#pragma unroll
    for (int j = 0; j < 8; j++){
      r0 += w[j] * b2f((ushort)t[j].x); r1 += w[j] * b2f((ushort)(t[j].x >> 16));
      r2 += w[j] * b2f((ushort)t[j].y); r3 += w[j] * b2f((ushort)(t[j].y >> 16));
    }
  }
  for (; i < d; i++){
    int u = nbr_all[o + i]; float w = wgt_all[o + i];
    uint2 t = xr[(size_t)u * 64 + lane];
    r0 += w * b2f((ushort)t.x); r1 += w * b2f((ushort)(t.x >> 16));
    r2 += w * b2f((ushort)t.y); r3 += w * b2f((ushort)(t.y >> 16));
  }

  uint2 out;
  out.x = (uint)f2b(r0) | ((uint)f2b(r1) << 16);
  out.y = (uint)f2b(r2) | ((uint)f2b(r3) << 16);
  ((uint2*)aggb)[(size_t)n * 64 + lane] = out;
}

// ---------------- fused 2-GEMM MLP layer (bf16 MFMA, swizzled 32KB LDS, M=64) ----
// xb: bf16 pre-activation state.  y = act(A@W1+b1)@W2+b2 ; v = (RESID? xb : 0) + y
// writes: xb = bf16(v) (if WRITE_X), axb = bf16(act(v)) — both coalesced 16B chunks.
template<int K1, bool RESID, bool GATHER, bool WRITE_X>
__global__ __launch_bounds__(256, 4) void k_fused_mlp(
    const ushort* __restrict__ Abase, const int* __restrict__ op_ids,
    const ushort* __restrict__ Wt1, const float* __restrict__ b1,
    const ushort* __restrict__ Wt2, const float* __restrict__ b2,
    ushort* __restrict__ xb, ushort* __restrict__ axb, int nN)
{
  __shared__ ushort smem[64 * 256];    // 32 KiB

  const int tid = threadIdx.x;
  const long m0 = (long)blockIdx.x * 64;
  const int wave = tid >> 6;
  const int lane = tid & 63;
  const int lr = lane & 15;
  const int lg = lane >> 4;
  const int n0 = wave * 64;
  const int aswz = (lr & 7) << 3;

  // ---- stage A-tile via global_load_lds (16B), inverse-swizzled source ----
  {
    constexpr int ROWB = K1 * 2;
    constexpr int ROUNDS = (64 * ROWB) / 4096;
    char* lds_c = (char*)smem;
#pragma unroll
    for (int rr = 0; rr < ROUNDS; rr++){
      int b = rr * 4096 + tid * 16;
      int row = b / ROWB;
      int colb = b % ROWB;
      long rg = m0 + row; if (rg >= nN) rg = nN - 1;
      long srow = GATHER ? (long)op_ids[rg] : rg;
      const char* src = (const char*)Abase + srow * ROWB + (colb ^ ((row & 7) << 4));
      gld_lds16(src, lds_c + b);
    }
  }
  __syncthreads();

  const ushort* w1r[4]; const ushort* w2r[4];
#pragma unroll
  for (int ni = 0; ni < 4; ni++){
    w1r[ni] = Wt1 + (size_t)(n0 + ni * 16 + lr) * K1;
    w2r[ni] = Wt2 + (size_t)(n0 + ni * 16 + lr) * 256;
  }

  // ---- GEMM1: A @ W1 ----
  f32x4 acc[4][4];
#pragma unroll
  for (int mi = 0; mi < 4; mi++)
#pragma unroll
    for (int ni = 0; ni < 4; ni++) acc[mi][ni] = (f32x4){0.f,0.f,0.f,0.f};

  for (int ks = 0; ks < K1 / 32; ks++){
    int k = ks * 32 + lg * 8;
    bf16x8 af[4], bfr[4];
#pragma unroll
    for (int mi = 0; mi < 4; mi++){
      int idx = ((mi * 16 + lr) * K1 + k) ^ aswz;
      af[mi] = *(const bf16x8*)&smem[idx];
    }
#pragma unroll
    for (int ni = 0; ni < 4; ni++)
      bfr[ni] = *(const bf16x8*)(w1r[ni] + k);
#pragma unroll
    for (int mi = 0; mi < 4; mi++)
#pragma unroll
      for (int ni = 0; ni < 4; ni++)
        acc[mi][ni] = __builtin_amdgcn_mfma_f32_16x16x32_bf16(af[mi], bfr[ni], acc[mi][ni], 0, 0, 0);
  }
  __syncthreads();   // A-tile consumed

  // ---- act + bf16 -> h-tile in same LDS ----
  float bb1[4];
#pragma unroll
  for (int ni = 0; ni < 4; ni++) bb1[ni] = b1[n0 + ni * 16 + lr];
#pragma unroll
  for (int mi = 0; mi < 4; mi++)
#pragma unroll
    for (int ni = 0; ni < 4; ni++)
#pragma unroll
      for (int r = 0; r < 4; r++){
        float v = actf(acc[mi][ni][r] + bb1[ni]);
        int row = mi * 16 + lg * 4 + r;
        int idx = (row * 256 + n0 + ni * 16 + lr) ^ ((row & 7) << 3);
        smem[idx] = f2b(v);
      }
  __syncthreads();

  // ---- GEMM2: h @ W2 ----
  f32x4 acc2[4][4];
#pragma unroll
  for (int mi = 0; mi < 4; mi++)
#pragma unroll
    for (int ni = 0; ni < 4; ni++) acc2[mi][ni] = (f32x4){0.f,0.f,0.f,0.f};

  for (int ks = 0; ks < 8; ks++){
    int k = ks * 32 + lg * 8;
    bf16x8 af[4], bfr[4];
#pragma unroll
    for (int mi = 0; mi < 4; mi++){
      int idx = ((mi * 16 + lr) * 256 + k) ^ aswz;
      af[mi] = *(const bf16x8*)&smem[idx];
    }
#pragma unroll
    for (int ni = 0; ni < 4; ni++)
      bfr[ni] = *(const bf16x8*)(w2r[ni] + k);
#pragma unroll
    for (int mi = 0; mi < 4; mi++)
#pragma unroll
      for (int ni = 0; ni < 4; ni++)
        acc2[mi][ni] = __builtin_amdgcn_mfma_f32_16x16x32_bf16(af[mi], bfr[ni], acc2[mi][ni], 0, 0, 0);
  }
  __syncthreads();   // h-tile consumed; smem reusable

  // ---- result tile (acc2 + b2, bf16) -> LDS, swizzled ----
  float bb2[4];
#pragma unroll
  for (int ni = 0; ni < 4; ni++) bb2[ni] = b2[n0 + ni * 16 + lr];
#pragma unroll
  for (int mi = 0; mi < 4; mi++)
#pragma unroll
    for (int ni = 0; ni < 4; ni++)
#pragma unroll
      for (int r = 0; r < 4; r++){
        int row = mi * 16 + lg * 4 + r;
        int idx = (row * 256 + n0 + ni * 16 + lr) ^ ((row & 7) << 3);
        smem[idx] = f2b(acc2[mi][ni][r] + bb2[ni]);
      }
  __syncthreads();

  // ---- coalesced epilogue: per 16B chunk, v = y + resid; xb=v, axb=act(v) ----
#pragma unroll
  for (int rr = 0; rr < 8; rr++){
    int b = rr * 4096 + tid * 16;
    int row = b >> 9;
    long rg = m0 + row;
    if (rg < nN){
      int rb = b & 511;
      uint4 hv = *(const uint4*)((const char*)smem + row * 512 + (rb ^ ((row & 7) << 4)));
      uint4 xv, av;
      const ushort* hp = (const ushort*)&hv;
      ushort* xp = (ushort*)&xv;
      ushort* ap = (ushort*)&av;
      if (RESID){
        uint4 rv = *(const uint4*)((const char*)xb + rg * 512 + rb);
        const ushort* rp = (const ushort*)&rv;
#pragma unroll
        for (int j = 0; j < 8; j++){
          float s = b2f(hp[j]) + b2f(rp[j]);
          xp[j] = f2b(s);
          ap[j] = f2b(actf(s));
        }
      } else {
#pragma unroll
        for (int j = 0; j < 8; j++){
          float s = b2f(hp[j]);
          xp[j] = hp[j];
          ap[j] = f2b(actf(s));
        }
      }
      if (WRITE_X) *(uint4*)((char*)xb + rg * 512 + rb) = xv;
      *(uint4*)((char*)axb + rg * 512 + rb) = av;
    }
  }
}

// ---------------- pooling: pooled[g] += axb[n] (act pre-applied, sorted gids) ----
__global__ __launch_bounds__(256) void k_pool(const ushort* __restrict__ axb,
                                              const int* __restrict__ gids,
                                              float* __restrict__ pooled, int nN){
  int j = threadIdx.x;
  int base = blockIdx.x * 256;
  if (base >= nN) return;
  int end = base + 256; if (end > nN) end = nN;
  float acc = 0.f;
  int gcur = gids[base];
  for (int n = base; n < end; n++){
    int g = gids[n];
    if (g != gcur){
      atomicAdd(&pooled[gcur * H + j], acc);
      acc = 0.f; gcur = g;
    }
    acc += b2f(axb[(size_t)n * H + j]);
  }
  atomicAdd(&pooled[gcur * H + j], acc);
}

// ---------------- post MLP ----------------
__global__ __launch_bounds__(256) void k_post(const float* __restrict__ pooled,
                                              const float* __restrict__ W1, const float* __restrict__ b1,
                                              const float* __restrict__ W2, const float* __restrict__ b2,
                                              float* __restrict__ out){
  __shared__ float sp[H];
  __shared__ float red[256];
  int g = blockIdx.x, j = threadIdx.x;
  sp[j] = pooled[g * H + j];
  __syncthreads();
  float acc = 0.f;
  for (int k = 0; k < H; k++) acc += sp[k] * W1[k * H + j];
  acc = actf(acc + b1[j]);
  red[j] = acc * W2[j];
  __syncthreads();
  for (int s = 128; s > 0; s >>= 1){
    if (j < s) red[j] += red[j + s];
    __syncthreads();
  }
  if (j == 0) out[g] = red[0] + b2[0];
}

extern "C" void kernel_launch(void* const* d_in, const int* in_sizes, int n_in,
                              void* d_out, int out_size, void* d_ws, size_t ws_size,
                              hipStream_t stream){
  const int*   op_ids = (const int*)d_in[0];
  const int*   esrc   = (const int*)d_in[1];
  const int*   edst   = (const int*)d_in[2];
  const int*   gids   = (const int*)d_in[3];
  const float* emb    = (const float*)d_in[4];
  const float* pW1    = (const float*)d_in[5];
  const float* pb1    = (const float*)d_in[6];
  const float* pW2    = (const float*)d_in[7];
  const float* pb2    = (const float*)d_in[8];
  const float* gW1    = (const float*)d_in[9];
  const float* gb1    = (const float*)d_in[10];
  const float* gW2    = (const float*)d_in[11];
  const float* gb2    = (const float*)d_in[12];
  const float* qW1    = (const float*)d_in[13];
  const float* qb1    = (const float*)d_in[14];
  const float* qW2    = (const float*)d_in[15];
  const float* qb2    = (const float*)d_in[16];

  int nN = in_sizes[0];
  int nE = in_sizes[1];
  int nG = out_size;
  int nEmb = in_sizes[4];

  char* ws = (char*)d_ws;
  size_t off = 0;
  auto alloc = [&](size_t bytes)->char* {
    char* p = ws + off;
    off += (bytes + 255) & ~(size_t)255;
    return p;
  };
  ushort* xb      = (ushort*)alloc((size_t)nN * H * 2);
  ushort* axb     = (ushort*)alloc((size_t)nN * H * 2);
  ushort* aggb    = (ushort*)alloc((size_t)nN * H * 2);
  float*  scale   = (float*) alloc((size_t)nN * 4);
  int*    nbr_all = (int*)   alloc((size_t)2 * nE * 4);
  float*  wgt_all = (float*) alloc((size_t)2 * nE * 4);
  int*    off_t   = (int*)   alloc((size_t)nN * 4);
  ushort* embb    = (ushort*)alloc((size_t)nEmb * 2);
  ushort* wtp1    = (ushort*)alloc((size_t)64 * 256 * 2);
  ushort* wtp2    = (ushort*)alloc((size_t)256 * 256 * 2);
  ushort* wtg     = (ushort*)alloc((size_t)6 * 256 * 256 * 2);
  char*   zbase   = ws + off;
  int*    deg_s   = (int*)   alloc((size_t)nN * 4);
  int*    deg_t   = (int*)   alloc((size_t)nN * 4);
  int*    cur     = (int*)   alloc((size_t)nN * 4);
  int*    ctr     = (int*)   alloc(256);
  float*  pooled  = (float*) alloc((size_t)nG * H * 4);
  size_t zbytes = (size_t)((ws + off) - zbase);

  hipMemsetAsync(zbase, 0, zbytes, stream);

  const int tb = 256;
  k_deg<<<(nE + tb - 1)/tb, tb, 0, stream>>>(esrc, edst, deg_s, deg_t, nE);
  k_scale_off<<<(nN + tb - 1)/tb, tb, 0, stream>>>(deg_s, deg_t, scale, off_t, ctr, nN);
  k_fill<<<(nE + tb - 1)/tb, tb, 0, stream>>>(esrc, edst, scale, off_t, cur, nbr_all, wgt_all, nE);

  k_cvt<<<(nEmb + 255)/256, 256, 0, stream>>>(emb, embb, nEmb);
  k_tpose<<<(64/32)*(256/32), 256, 0, stream>>>(pW1, wtp1, 64, 256);
  k_tpose<<<(256/32)*(256/32), 256, 0, stream>>>(pW2, wtp2, 256, 256);
  for (int i = 0; i < 3; i++){
    k_tpose<<<64, 256, 0, stream>>>(gW1 + (size_t)i*65536, wtg + (size_t)(2*i)*65536, 256, 256);
    k_tpose<<<64, 256, 0, stream>>>(gW2 + (size_t)i*65536, wtg + (size_t)(2*i+1)*65536, 256, 256);
  }

  int gblk = (nN + 63) / 64;
  // prenet: xb = prenet(emb[op]), axb = act(xb)
  k_fused_mlp<64, false, true, true><<<gblk, 256, 0, stream>>>(
      embb, op_ids, wtp1, pb1, wtp2, pb2, xb, axb, nN);

  // GNN layers 1,2: write xb + axb; layer 3: axb only (x unused afterwards)
  k_agg<<<(nN + 3)/4, 256, 0, stream>>>(axb, aggb, scale, off_t, deg_t, nbr_all, wgt_all, nN);
  k_fused_mlp<256, true, false, true><<<gblk, 256, 0, stream>>>(
      aggb, op_ids, wtg + (size_t)0*65536, gb1 + (size_t)0*H,
      wtg + (size_t)1*65536, gb2 + (size_t)0*H, xb, axb, nN);

  k_agg<<<(nN + 3)/4, 256, 0, stream>>>(axb, aggb, scale, off_t, deg_t, nbr_all, wgt_all, nN);
  k_fused_mlp<256, true, false, true><<<gblk, 256, 0, stream>>>(
      aggb, op_ids, wtg + (size_t)2*65536, gb1 + (size_t)1*H,
      wtg + (size_t)3*65536, gb2 + (size_t)1*H, xb, axb, nN);

  k_agg<<<(nN + 3)/4, 256, 0, stream>>>(axb, aggb, scale, off_t, deg_t, nbr_all, wgt_all, nN);
  k_fused_mlp<256, true, false, false><<<gblk, 256, 0, stream>>>(
      aggb, op_ids, wtg + (size_t)4*65536, gb1 + (size_t)2*H,
      wtg + (size_t)5*65536, gb2 + (size_t)2*H, xb, axb, nN);

  k_pool<<<(nN + 255)/256, 256, 0, stream>>>(axb, gids, pooled, nN);
  k_post<<<nG, 256, 0, stream>>>(pooled, qW1, qb1, qW2, qb2, (float*)d_out);
}

// Round 12
// 1048.122 us; speedup vs baseline: 1.3002x; 1.0920x over previous
//
#include <hip/hip_runtime.h>
#include <cstdint>

#define ALPHA 0.2f
#define H 256

typedef __attribute__((ext_vector_type(8))) short bf16x8;
typedef __attribute__((ext_vector_type(4))) float f32x4;

__device__ __forceinline__ float actf(float v){ return v > 0.0f ? v : ALPHA * v; }

__device__ __forceinline__ ushort f2b(float f){
  union { float f; uint u; } x; x.f = f;
  uint u = x.u + 0x7FFF + ((x.u >> 16) & 1);   // RNE
  return (ushort)(u >> 16);
}
__device__ __forceinline__ float b2f(ushort h){
  union { uint u; float f; } x; x.u = (uint)h << 16; return x.f;
}

__device__ __forceinline__ void gld_lds16(const void* g, void* l){
  __builtin_amdgcn_global_load_lds((const __attribute__((address_space(1))) void*)g,
                                   (__attribute__((address_space(3))) void*)l, 16, 0, 0);
}

// ---------------- CSR build (combined weighted neighbor list) ----------------
__global__ void k_deg(const int* __restrict__ src, const int* __restrict__ dst,
                      int* __restrict__ deg_s, int* __restrict__ deg_t, int nE){
  int e = blockIdx.x * blockDim.x + threadIdx.x;
  if (e < nE){
    atomicAdd(&deg_s[src[e]], 1);
    atomicAdd(&deg_t[src[e]], 1);
    atomicAdd(&deg_t[dst[e]], 1);
  }
}

__global__ void k_scale_off(const int* __restrict__ deg_s, const int* __restrict__ deg_t,
                            float* __restrict__ scale, int* __restrict__ off_t,
                            int* __restrict__ ctr, int nN){
  int n = blockIdx.x * blockDim.x + threadIdx.x;
  if (n < nN){
    scale[n] = 1.0f / (1.0f + (float)deg_s[n]);
    off_t[n] = atomicAdd(&ctr[0], deg_t[n]);
  }
}

__global__ void k_fill(const int* __restrict__ src, const int* __restrict__ dst,
                       const float* __restrict__ scale,
                       const int* __restrict__ off_t, int* __restrict__ cur,
                       int* __restrict__ nbr_all, float* __restrict__ wgt_all, int nE){
  int e = blockIdx.x * blockDim.x + threadIdx.x;
  if (e < nE){
    int s = src[e], d = dst[e];
    float w = scale[s];
    int p = atomicAdd(&cur[d], 1);
    int idx = off_t[d] + p;
    nbr_all[idx] = s; wgt_all[idx] = w;
    int q = atomicAdd(&cur[s], 1);
    idx = off_t[s] + q;
    nbr_all[idx] = d; wgt_all[idx] = w;
  }
}

// ---------------- coalesced weight transpose: Wt[n][k] = bf16(W[k][n]) ----------------
__global__ __launch_bounds__(256) void k_tpose(const float* __restrict__ W,
                                               ushort* __restrict__ Wt, int K, int N){
  __shared__ ushort tile[32][33];
  int nt = N >> 5;
  int tr = blockIdx.x / nt, tc = blockIdx.x % nt;
  int r = threadIdx.x >> 5, c = threadIdx.x & 31;
#pragma unroll
  for (int i = 0; i < 4; i++){
    int rr = r + i * 8;
    tile[rr][c] = f2b(W[(size_t)(tr * 32 + rr) * N + tc * 32 + c]);
  }
  __syncthreads();
#pragma unroll
  for (int i = 0; i < 4; i++){
    int rr = r + i * 8;
    Wt[(size_t)(tc * 32 + rr) * K + tr * 32 + c] = tile[c][rr];
  }
}

__global__ void k_cvt(const float* __restrict__ src, ushort* __restrict__ dst, int n){
  int i = blockIdx.x * 256 + threadIdx.x;
  if (i < n) dst[i] = f2b(src[i]);
}

// ---------------- fused 2-GEMM MLP layer (bf16 MFMA, swizzled 32KB LDS) ----------------
// R4-proven structure. y = act(A@W1+b1)@W2+b2 ; v = (RESID? x : 0) + y ;
// x = v (f32, if WRITE_X) ; axb = bf16(act(v)).  Scalar interleaved epilogue.
template<int K1, bool RESID, bool GATHER, bool WRITE_X>
__global__ __launch_bounds__(256) void k_fused_mlp(
    const ushort* __restrict__ Abase, const int* __restrict__ op_ids,
    const ushort* __restrict__ Wt1, const float* __restrict__ b1,
    const ushort* __restrict__ Wt2, const float* __restrict__ b2,
    float* __restrict__ x, ushort* __restrict__ axb, int nN)
{
  __shared__ ushort smem[64 * 256];    // 32 KiB

  const int tid = threadIdx.x;
  const long m0 = (long)blockIdx.x * 64;

  // ---- stage A-tile: 64 rows x K1 bf16 via global_load_lds (16B), swizzled src ----
  {
    constexpr int ROWB = K1 * 2;
    constexpr int ROUNDS = (64 * ROWB) / 4096;
    char* lds_c = (char*)smem;
#pragma unroll
    for (int rr = 0; rr < ROUNDS; rr++){
      int b = rr * 4096 + tid * 16;
      int row = b / ROWB;
      int colb = b % ROWB;
      long rg = m0 + row; if (rg >= nN) rg = nN - 1;
      long srow = GATHER ? (long)op_ids[rg] : rg;
      const char* src = (const char*)Abase + srow * ROWB + (colb ^ ((row & 7) << 4));
      gld_lds16(src, lds_c + b);
    }
  }
  __syncthreads();

  const int wave = tid >> 6;
  const int lane = tid & 63;
  const int lr = lane & 15;
  const int lg = lane >> 4;
  const int n0 = wave * 64;
  const int aswz = (lr & 7) << 3;     // read-side swizzle

  const ushort* w1r[4]; const ushort* w2r[4];
#pragma unroll
  for (int ni = 0; ni < 4; ni++){
    w1r[ni] = Wt1 + (size_t)(n0 + ni * 16 + lr) * K1;
    w2r[ni] = Wt2 + (size_t)(n0 + ni * 16 + lr) * 256;
  }

  // ---- GEMM1: A @ W1 ----
  f32x4 acc[4][4];
#pragma unroll
  for (int mi = 0; mi < 4; mi++)
#pragma unroll
    for (int ni = 0; ni < 4; ni++) acc[mi][ni] = (f32x4){0.f,0.f,0.f,0.f};

  for (int ks = 0; ks < K1 / 32; ks++){
    int k = ks * 32 + lg * 8;
    bf16x8 af[4], bfr[4];
#pragma unroll
    for (int mi = 0; mi < 4; mi++){
      int idx = ((mi * 16 + lr) * K1 + k) ^ aswz;
      af[mi] = *(const bf16x8*)&smem[idx];
    }
#pragma unroll
    for (int ni = 0; ni < 4; ni++)
      bfr[ni] = *(const bf16x8*)(w1r[ni] + k);
#pragma unroll
    for (int mi = 0; mi < 4; mi++)
#pragma unroll
      for (int ni = 0; ni < 4; ni++)
        acc[mi][ni] = __builtin_amdgcn_mfma_f32_16x16x32_bf16(af[mi], bfr[ni], acc[mi][ni], 0, 0, 0);
  }
  __syncthreads();   // all waves done reading A-tile

  // ---- act + bf16 -> h-tile in same LDS (semantic [64][256], same swizzle) ----
  float bb1[4];
#pragma unroll
  for (int ni = 0; ni < 4; ni++) bb1[ni] = b1[n0 + ni * 16 + lr];
#pragma unroll
  for (int mi = 0; mi < 4; mi++)
#pragma unroll
    for (int ni = 0; ni < 4; ni++)
#pragma unroll
      for (int r = 0; r < 4; r++){
        float v = actf(acc[mi][ni][r] + bb1[ni]);
        int row = mi * 16 + lg * 4 + r;
        int idx = (row * 256 + n0 + ni * 16 + lr) ^ ((row & 7) << 3);
        smem[idx] = f2b(v);
      }
  __syncthreads();

  // ---- GEMM2: h @ W2 ----
  f32x4 acc2[4][4];
#pragma unroll
  for (int mi = 0; mi < 4; mi++)
#pragma unroll
    for (int ni = 0; ni < 4; ni++) acc2[mi][ni] = (f32x4){0.f,0.f,0.f,0.f};

  for (int ks = 0; ks < 8; ks++){
    int k = ks * 32 + lg * 8;
    bf16x8 af[4], bfr[4];
#pragma unroll
    for (int mi = 0; mi < 4; mi++){
      int idx = ((mi * 16 + lr) * 256 + k) ^ aswz;
      af[mi] = *(const bf16x8*)&smem[idx];
    }
#pragma unroll
    for (int ni = 0; ni < 4; ni++)
      bfr[ni] = *(const bf16x8*)(w2r[ni] + k);
#pragma unroll
    for (int mi = 0; mi < 4; mi++)
#pragma unroll
      for (int ni = 0; ni < 4; ni++)
        acc2[mi][ni] = __builtin_amdgcn_mfma_f32_16x16x32_bf16(af[mi], bfr[ni], acc2[mi][ni], 0, 0, 0);
  }

  // ---- epilogue (R4-proven scalar interleave): + b2 (+x), write x f32 / axb bf16 ----
  float bb2[4];
#pragma unroll
  for (int ni = 0; ni < 4; ni++) bb2[ni] = b2[n0 + ni * 16 + lr];
#pragma unroll
  for (int mi = 0; mi < 4; mi++)
#pragma unroll
    for (int r = 0; r < 4; r++){
      long row = m0 + mi * 16 + lg * 4 + r;
      if (row < nN){
#pragma unroll
        for (int ni = 0; ni < 4; ni++){
          size_t idx = (size_t)row * 256 + n0 + ni * 16 + lr;
          float v = acc2[mi][ni][r] + bb2[ni];
          if (RESID) v += x[idx];
          if (WRITE_X) x[idx] = v;
          axb[idx] = f2b(actf(v));
        }
      }
    }
}

// ---------------- aggregation (R4-proven): merged weighted CSR, unroll x8 ----------------
// aggb[n] = bf16( sum_i w_i * a[nbr_i] + (2*scale[n]+1) * a[n] ),  a = axb (pre-activated)
__global__ __launch_bounds__(256) void k_agg(
    const ushort* __restrict__ axb, ushort* __restrict__ aggb, const float* __restrict__ scale,
    const int* __restrict__ off_t, const int* __restrict__ deg_t,
    const int* __restrict__ nbr_all, const float* __restrict__ wgt_all, int nN){
  int wave = threadIdx.x >> 6;
  int lane = threadIdx.x & 63;
  int n = blockIdx.x * 4 + wave;
  if (n >= nN) return;
  const uint2* xr = (const uint2*)axb;
  float sn = scale[n];

  uint2 v = xr[(size_t)n * 64 + lane];
  float c = 2.f * sn + 1.f;
  float r0 = c * b2f((ushort)v.x), r1 = c * b2f((ushort)(v.x >> 16));
  float r2 = c * b2f((ushort)v.y), r3 = c * b2f((ushort)(v.y >> 16));

  const int o = off_t[n], d = deg_t[n];
  int i = 0;
  for (; i + 8 <= d; i += 8){
    int u[8]; float w[8];
#pragma unroll
    for (int j = 0; j < 8; j++){ u[j] = nbr_all[o + i + j]; w[j] = wgt_all[o + i + j]; }
    uint2 t[8];
#pragma unroll
    for (int j = 0; j < 8; j++) t[j] = xr[(size_t)u[j] * 64 + lane];
#pragma unroll
    for (int j = 0; j < 8; j++){
      r0 += w[j] * b2f((ushort)t[j].x); r1 += w[j] * b2f((ushort)(t[j].x >> 16));
      r2 += w[j] * b2f((ushort)t[j].y); r3 += w[j] * b2f((ushort)(t[j].y >> 16));
    }
  }
  for (; i < d; i++){
    int u = nbr_all[o + i]; float w = wgt_all[o + i];
    uint2 t = xr[(size_t)u * 64 + lane];
    r0 += w * b2f((ushort)t.x); r1 += w * b2f((ushort)(t.x >> 16));
    r2 += w * b2f((ushort)t.y); r3 += w * b2f((ushort)(t.y >> 16));
  }

  uint2 out;
  out.x = (uint)f2b(r0) | ((uint)f2b(r1) << 16);
  out.y = (uint)f2b(r2) | ((uint)f2b(r3) << 16);
  ((uint2*)aggb)[(size_t)n * 64 + lane] = out;
}

// ---------------- pooling: pooled[g] += axb[n] (act pre-applied, sorted gids) ----
__global__ __launch_bounds__(256) void k_pool(const ushort* __restrict__ axb,
                                              const int* __restrict__ gids,
                                              float* __restrict__ pooled, int nN){
  int j = threadIdx.x;
  int base = blockIdx.x * 256;
  if (base >= nN) return;
  int end = base + 256; if (end > nN) end = nN;
  float acc = 0.f;
  int gcur = gids[base];
  for (int n = base; n < end; n++){
    int g = gids[n];
    if (g != gcur){
      atomicAdd(&pooled[gcur * H + j], acc);
      acc = 0.f; gcur = g;
    }
    acc += b2f(axb[(size_t)n * H + j]);
  }
  atomicAdd(&pooled[gcur * H + j], acc);
}

// ---------------- post MLP ----------------
__global__ __launch_bounds__(256) void k_post(const float* __restrict__ pooled,
                                              const float* __restrict__ W1, const float* __restrict__ b1,
                                              const float* __restrict__ W2, const float* __restrict__ b2,
                                              float* __restrict__ out){
  __shared__ float sp[H];
  __shared__ float red[256];
  int g = blockIdx.x, j = threadIdx.x;
  sp[j] = pooled[g * H + j];
  __syncthreads();
  float acc = 0.f;
  for (int k = 0; k < H; k++) acc += sp[k] * W1[k * H + j];
  acc = actf(acc + b1[j]);
  red[j] = acc * W2[j];
  __syncthreads();
  for (int s = 128; s > 0; s >>= 1){
    if (j < s) red[j] += red[j + s];
    __syncthreads();
  }
  if (j == 0) out[g] = red[0] + b2[0];
}

extern "C" void kernel_launch(void* const* d_in, const int* in_sizes, int n_in,
                              void* d_out, int out_size, void* d_ws, size_t ws_size,
                              hipStream_t stream){
  const int*   op_ids = (const int*)d_in[0];
  const int*   esrc   = (const int*)d_in[1];
  const int*   edst   = (const int*)d_in[2];
  const int*   gids   = (const int*)d_in[3];
  const float* emb    = (const float*)d_in[4];
  const float* pW1    = (const float*)d_in[5];
  const float* pb1    = (const float*)d_in[6];
  const float* pW2    = (const float*)d_in[7];
  const float* pb2    = (const float*)d_in[8];
  const float* gW1    = (const float*)d_in[9];
  const float* gb1    = (const float*)d_in[10];
  const float* gW2    = (const float*)d_in[11];
  const float* gb2    = (const float*)d_in[12];
  const float* qW1    = (const float*)d_in[13];
  const float* qb1    = (const float*)d_in[14];
  const float* qW2    = (const float*)d_in[15];
  const float* qb2    = (const float*)d_in[16];

  int nN = in_sizes[0];
  int nE = in_sizes[1];
  int nG = out_size;
  int nEmb = in_sizes[4];

  char* ws = (char*)d_ws;
  size_t off = 0;
  auto alloc = [&](size_t bytes)->char* {
    char* p = ws + off;
    off += (bytes + 255) & ~(size_t)255;
    return p;
  };
  float*  x       = (float*) alloc((size_t)nN * H * 4);
  ushort* axb     = (ushort*)alloc((size_t)nN * H * 2);
  ushort* aggb    = (ushort*)alloc((size_t)nN * H * 2);
  float*  scale   = (float*) alloc((size_t)nN * 4);
  int*    nbr_all = (int*)   alloc((size_t)2 * nE * 4);
  float*  wgt_all = (float*) alloc((size_t)2 * nE * 4);
  int*    off_t   = (int*)   alloc((size_t)nN * 4);
  ushort* embb    = (ushort*)alloc((size_t)nEmb * 2);
  ushort* wtp1    = (ushort*)alloc((size_t)64 * 256 * 2);
  ushort* wtp2    = (ushort*)alloc((size_t)256 * 256 * 2);
  ushort* wtg     = (ushort*)alloc((size_t)6 * 256 * 256 * 2);
  char*   zbase   = ws + off;
  int*    deg_s   = (int*)   alloc((size_t)nN * 4);
  int*    deg_t   = (int*)   alloc((size_t)nN * 4);
  int*    cur     = (int*)   alloc((size_t)nN * 4);
  int*    ctr     = (int*)   alloc(256);
  float*  pooled  = (float*) alloc((size_t)nG * H * 4);
  size_t zbytes = (size_t)((ws + off) - zbase);

  hipMemsetAsync(zbase, 0, zbytes, stream);

  const int tb = 256;
  k_deg<<<(nE + tb - 1)/tb, tb, 0, stream>>>(esrc, edst, deg_s, deg_t, nE);
  k_scale_off<<<(nN + tb - 1)/tb, tb, 0, stream>>>(deg_s, deg_t, scale, off_t, ctr, nN);
  k_fill<<<(nE + tb - 1)/tb, tb, 0, stream>>>(esrc, edst, scale, off_t, cur, nbr_all, wgt_all, nE);

  k_cvt<<<(nEmb + 255)/256, 256, 0, stream>>>(emb, embb, nEmb);
  k_tpose<<<(64/32)*(256/32), 256, 0, stream>>>(pW1, wtp1, 64, 256);
  k_tpose<<<(256/32)*(256/32), 256, 0, stream>>>(pW2, wtp2, 256, 256);
  for (int i = 0; i < 3; i++){
    k_tpose<<<64, 256, 0, stream>>>(gW1 + (size_t)i*65536, wtg + (size_t)(2*i)*65536, 256, 256);
    k_tpose<<<64, 256, 0, stream>>>(gW2 + (size_t)i*65536, wtg + (size_t)(2*i+1)*65536, 256, 256);
  }

  int gblk = (nN + 63) / 64;
  // prenet: x = prenet(emb[op]); axb = act(x)
  k_fused_mlp<64, false, true, true><<<gblk, 256, 0, stream>>>(
      embb, op_ids, wtp1, pb1, wtp2, pb2, x, axb, nN);

  // layers 1,2: write x + axb ; layer 3: axb only (x dead afterwards)
  k_agg<<<(nN + 3)/4, 256, 0, stream>>>(axb, aggb, scale, off_t, deg_t, nbr_all, wgt_all, nN);
  k_fused_mlp<256, true, false, true><<<gblk, 256, 0, stream>>>(
      aggb, op_ids, wtg + (size_t)0*65536, gb1 + (size_t)0*H,
      wtg + (size_t)1*65536, gb2 + (size_t)0*H, x, axb, nN);

  k_agg<<<(nN + 3)/4, 256, 0, stream>>>(axb, aggb, scale, off_t, deg_t, nbr_all, wgt_all, nN);
  k_fused_mlp<256, true, false, true><<<gblk, 256, 0, stream>>>(
      aggb, op_ids, wtg + (size_t)2*65536, gb1 + (size_t)1*H,
      wtg + (size_t)3*65536, gb2 + (size_t)1*H, x, axb, nN);

  k_agg<<<(nN + 3)/4, 256, 0, stream>>>(axb, aggb, scale, off_t, deg_t, nbr_all, wgt_all, nN);
  k_fused_mlp<256, true, false, false><<<gblk, 256, 0, stream>>>(
      aggb, op_ids, wtg + (size_t)4*65536, gb1 + (size_t)2*H,
      wtg + (size_t)5*65536, gb2 + (size_t)2*H, x, axb, nN);

  k_pool<<<(nN + 255)/256, 256, 0, stream>>>(axb, gids, pooled, nN);
  k_post<<<nG, 256, 0, stream>>>(pooled, qW1, qb1, qW2, qb2, (float*)d_out);
}